// Round 10
// baseline (969.160 us; speedup 1.0000x reference)
//
#include <hip/hip_runtime.h>
#include <hip/hip_bf16.h>
#include <stdint.h>

// Inputs may be float32 OR bf16 (detected at runtime on-device); internal
// canonical dtype is bf16; compute in fp32; output emitted in detected dtype.
typedef __bf16 bf16_t;
typedef __bf16 bf16x8 __attribute__((ext_vector_type(8)));
typedef float  f32x4  __attribute__((ext_vector_type(4)));

typedef __attribute__((address_space(3))) unsigned int lds_u32;
typedef const __attribute__((address_space(1))) unsigned int glob_u32;
#define GLDS16(g, l) __builtin_amdgcn_global_load_lds((glob_u32*)(g), (lds_u32*)(l), 16, 0, 0)

__device__ __forceinline__ f32x4 mfma16(bf16x8 a, bf16x8 b, f32x4 c) {
    // D[row=quad*4+r][col=lane&15]; A[row=lane&15][k=quad*8+j]; B[k=quad*8+j][col=lane&15]
    return __builtin_amdgcn_mfma_f32_16x16x32_bf16(a, b, c, 0, 0, 0);
}

__device__ __forceinline__ float ldv(const void* p, long i, int fp32mode) {
    return fp32mode ? ((const float*)p)[i] : (float)((const bf16_t*)p)[i];
}

// ---------------------------------------------------------------- dtype detect
__global__ __launch_bounds__(256)
void detect_dtype(const void* __restrict__ x, int* __restrict__ flag) {
    __shared__ int cnt;
    if (threadIdx.x == 0) cnt = 0;
    __syncthreads();
    const bf16_t* p = (const bf16_t*)x;
    int local = 0;
    for (int i = threadIdx.x; i < 4096; i += 256) {
        const float v = (float)p[i];
        if (!(fabsf(v) < 1e6f)) local++;   // catches NaN too
    }
    atomicAdd(&cnt, local);
    __syncthreads();
    if (threadIdx.x == 0) { flag[0] = (cnt >= 16) ? 1 : 0; flag[1] = 0; }
}

// ---------------------------------------------------------------- convert-transpose (batched)
__global__ __launch_bounds__(256)
void transpose_cvt(const void* __restrict__ in, bf16_t* __restrict__ out,
                   int R, int C, const int* __restrict__ flagp) {
    __shared__ bf16_t t[32][33];
    const int mode = *flagp;
    const long zi = (long)blockIdx.z * R * C;
    const int c0 = blockIdx.x * 32;
    const int r0 = blockIdx.y * 32;
    const int x  = threadIdx.x;
    const int y0 = threadIdx.y;
    for (int yy = y0; yy < 32; yy += 8)
        t[yy][x] = (bf16_t)ldv(in, zi + (long)(r0 + yy) * C + c0 + x, mode);
    __syncthreads();
    for (int yy = y0; yy < 32; yy += 8)
        out[zi + (long)(c0 + yy) * R + r0 + x] = t[x][yy];
}

// ---------------------------------------------------------------- wv permuted transpose
// W2T[e][h*768+k] = wv[k][h*768+e]   (both ld 9216)
__global__ __launch_bounds__(256)
void transpose_wv(const void* __restrict__ in, bf16_t* __restrict__ out,
                  const int* __restrict__ flagp) {
    __shared__ bf16_t t[32][33];
    const int mode = *flagp;
    const int h  = blockIdx.z;
    const int e0 = blockIdx.x * 32;
    const int k0 = blockIdx.y * 32;
    const int x  = threadIdx.x;
    const int y0 = threadIdx.y;
    for (int yy = y0; yy < 32; yy += 8)
        t[yy][x] = (bf16_t)ldv(in, (long)(k0 + yy) * 9216 + h * 768 + e0 + x, mode);
    __syncthreads();
    for (int yy = y0; yy < 32; yy += 8)
        out[(long)(e0 + yy) * 9216 + h * 768 + k0 + x] = t[x][yy];
}

// ---------------------------------------------------------------- bv head-sum
__global__ __launch_bounds__(256)
void bvsum_k(const void* __restrict__ bv, float* __restrict__ out,
             const int* __restrict__ flagp) {
    const int mode = *flagp;
    const int e = blockIdx.x * 256 + threadIdx.x;
    if (e < 768) {
        float s = 0.f;
#pragma unroll
        for (int h = 0; h < 12; ++h) s += ldv(bv, h * 768 + e, mode);
        out[e] = s;
    }
}

// ---------------------------------------------------------------- layernorm (768 cols)
__global__ __launch_bounds__(256)
void ln768(const void* __restrict__ in, bf16_t* __restrict__ out,
           const void* __restrict__ gam, const void* __restrict__ bet,
           const int* __restrict__ dmodep, const int* __restrict__ pmodep) {
    __shared__ float rs[256], rq[256];
    const int dm = *dmodep, pm = *pmodep;
    const long base = (long)blockIdx.x * 768;
    const int tid = threadIdx.x;
    float v[3];
    float s = 0.f, q = 0.f;
#pragma unroll
    for (int i = 0; i < 3; ++i) {
        v[i] = ldv(in, base + i * 256 + tid, dm);
        s += v[i];
        q += v[i] * v[i];
    }
    rs[tid] = s; rq[tid] = q;
    __syncthreads();
    for (int st = 128; st > 0; st >>= 1) {
        if (tid < st) { rs[tid] += rs[tid + st]; rq[tid] += rq[tid + st]; }
        __syncthreads();
    }
    const float mean = rs[0] * (1.0f / 768.0f);
    const float var  = rq[0] * (1.0f / 768.0f) - mean * mean;
    const float rstd = rsqrtf(var + 1e-5f);
#pragma unroll
    for (int i = 0; i < 3; ++i) {
        const int c = i * 256 + tid;
        out[base + c] = (bf16_t)((v[i] - mean) * rstd * ldv(gam, c, pm) + ldv(bet, c, pm));
    }
}

// ================================================================ GEMM engines
// m97-staging (r8-proven): global_load_lds width-16 into LINEAR LDS, SINGLE
// buffer, 2 barriers/K-step, both-sides XOR swizzle (source col ^((row&7)<<4),
// same XOR on ds_read_b128) -> zero bank conflicts (r8 PMC).
//
// Two tiles:
//  kloop64 : 64x128, 4 waves of 64x32, acc[4][2] (1.33 MFMA per ds_read) —
//            for grids that need block count (qk/bt: 768-1536 blocks).
//  kloop128: 128x128, 4 waves (2x2) of 64x64, acc[4][4] (2.0 MFMA/read, the
//            m97 ratio; 874 TF at ~12 waves/CU on the learn_hip ladder) —
//            for vt (1536 blocks via batch*head) and dx (768 via split-K).
// r8 measured acc[4][2]@12w/CU = 592 TF, LDS-read-bound; the ratio is the gap.
__device__ __forceinline__ void kloop64(const bf16_t* Az, const bf16_t* Bz,
                                        int K, int lda, int ldb, int tid,
                                        char* As, char* Bs,
                                        int wn, int l15, int quad,
                                        f32x4 (&acc)[4][2]) {
    const int srow = tid >> 3;                               // 0..31
    const int sc   = ((tid & 7) * 16) ^ ((srow & 7) << 4);   // pre-swizzled src col
    char* lA = As + (tid >> 6) * 1024;   // wave-uniform dest base (+lane*16 by HW)
    char* lB = Bs + (tid >> 6) * 1024;
    const int rsw = (l15 & 7) << 4;      // read-side XOR
    for (int k0 = 0; k0 < K; k0 += 64) {
        __syncthreads();
        GLDS16((const char*)(Az + (long)srow * lda + k0) + sc, lA);
        GLDS16((const char*)(Az + (long)(srow + 32) * lda + k0) + sc, lA + 4096);
#pragma unroll
        for (int p = 0; p < 4; ++p)
            GLDS16((const char*)(Bz + (long)(srow + p * 32) * ldb + k0) + sc, lB + p * 4096);
        __syncthreads();
#pragma unroll
        for (int kk = 0; kk < 64; kk += 32) {
            bf16x8 af[4], bfr[2];
            const int cb = kk * 2 + quad * 16;
#pragma unroll
            for (int i = 0; i < 4; ++i)
                af[i] = *(const bf16x8*)(As + (i * 16 + l15) * 128 + (cb ^ rsw));
#pragma unroll
            for (int j = 0; j < 2; ++j)
                bfr[j] = *(const bf16x8*)(Bs + (wn + j * 16 + l15) * 128 + (cb ^ rsw));
#pragma unroll
            for (int i = 0; i < 4; ++i)
#pragma unroll
                for (int j = 0; j < 2; ++j)
                    acc[i][j] = mfma16(af[i], bfr[j], acc[i][j]);
        }
    }
}

__device__ __forceinline__ void kloop128(const bf16_t* Az, const bf16_t* Bz,
                                         int K, int lda, int ldb, int tid,
                                         char* As, char* Bs,
                                         int wm, int wn, int l15, int quad,
                                         f32x4 (&acc)[4][4]) {
    const int srow = tid >> 3;                               // 0..31
    const int sc   = ((tid & 7) * 16) ^ ((srow & 7) << 4);
    char* lA = As + (tid >> 6) * 1024;
    char* lB = Bs + (tid >> 6) * 1024;
    const int rsw = (l15 & 7) << 4;
    for (int k0 = 0; k0 < K; k0 += 64) {
        __syncthreads();
#pragma unroll
        for (int p = 0; p < 4; ++p) {
            GLDS16((const char*)(Az + (long)(srow + p * 32) * lda + k0) + sc, lA + p * 4096);
            GLDS16((const char*)(Bz + (long)(srow + p * 32) * ldb + k0) + sc, lB + p * 4096);
        }
        __syncthreads();
#pragma unroll
        for (int kk = 0; kk < 64; kk += 32) {
            bf16x8 af[4], bfr[4];
            const int cb = kk * 2 + quad * 16;
#pragma unroll
            for (int i = 0; i < 4; ++i)
                af[i] = *(const bf16x8*)(As + (wm + i * 16 + l15) * 128 + (cb ^ rsw));
#pragma unroll
            for (int j = 0; j < 4; ++j)
                bfr[j] = *(const bf16x8*)(Bs + (wn + j * 16 + l15) * 128 + (cb ^ rsw));
#pragma unroll
            for (int i = 0; i < 4; ++i)
#pragma unroll
                for (int j = 0; j < 4; ++j)
                    acc[i][j] = mfma16(af[i], bfr[j], acc[i][j]);
        }
    }
}

// bijective XCD chunk swizzle over nwg blocks (nwg % 8 == 0)
__device__ __forceinline__ int xcd_swz(int lin, int nwg) {
    return (lin & 7) * (nwg >> 3) + (lin >> 3);
}

// ---------------------------------------------------------------- generic GEMM C = A*B^T (bf16 out)
// 64x128 tiles; grid (6, 128) = 768 blocks = 3/CU, one exact round.
__global__ __launch_bounds__(256)
void gemm_bt(const bf16_t* __restrict__ A, const bf16_t* __restrict__ B,
             bf16_t* __restrict__ C,
             int K, int lda, int ldb, int ldc,
             const void* __restrict__ bias, const int* __restrict__ flagp,
             const bf16_t* __restrict__ res, int do_relu) {
    __shared__ char As[64 * 128];
    __shared__ char Bs[128 * 128];
    const int bmode = *flagp;
    const int swz = xcd_swz(blockIdx.y * 6 + blockIdx.x, 768);
    const int n0 = (swz % 6) * 128;
    const int m0 = (swz / 6) * 64;
    const bf16_t* Az = A + (long)m0 * lda;
    const bf16_t* Bz = B + (long)n0 * ldb;

    const int tid  = threadIdx.x;
    const int lane = tid & 63;
    const int wn   = (tid >> 6) * 32;
    const int l15  = lane & 15;
    const int quad = lane >> 4;

    const f32x4 fz = {0.f, 0.f, 0.f, 0.f};
    f32x4 acc[4][2];
#pragma unroll
    for (int i = 0; i < 4; ++i)
#pragma unroll
        for (int j = 0; j < 2; ++j) acc[i][j] = fz;

    kloop64(Az, Bz, K, lda, ldb, tid, As, Bs, wn, l15, quad, acc);

#pragma unroll
    for (int i = 0; i < 4; ++i) {
#pragma unroll
        for (int j = 0; j < 2; ++j) {
            const int mb = m0 + i * 16 + quad * 4;
            const int nc = n0 + wn + j * 16 + l15;
#pragma unroll
            for (int r = 0; r < 4; ++r) {
                float v = acc[i][j][r];
                if (bias) v += ldv(bias, nc, bmode);
                if (do_relu) v = fmaxf(v, 0.0f);
                if (res) v += (float)res[(long)(mb + r) * ldc + nc];
                C[(long)(mb + r) * ldc + nc] = (bf16_t)v;
            }
        }
    }
}

// ---------------------------------------------------------------- merged Q/K projection (64x128)
__global__ __launch_bounds__(256)
void gemm_qk(const bf16_t* __restrict__ xn, const bf16_t* __restrict__ ynb,
             const bf16_t* __restrict__ wqT, const bf16_t* __restrict__ wkT,
             bf16_t* __restrict__ qb, bf16_t* __restrict__ kb,
             const void* __restrict__ bq, const void* __restrict__ bk,
             const int* __restrict__ flagp) {
    __shared__ char As[64 * 128];
    __shared__ char Bs[128 * 128];
    const int bmode = *flagp;
    const int z = blockIdx.z;
    const bf16_t* A = z ? ynb : xn;
    const bf16_t* B = z ? wkT : wqT;
    bf16_t*       C = z ? kb  : qb;
    const void* bias = z ? bk : bq;
    const int swz = xcd_swz(blockIdx.y * 6 + blockIdx.x, 768);
    const int n0 = (swz % 6) * 128;
    const int m0 = (swz / 6) * 64;
    const bf16_t* Az = A + (long)m0 * 768;
    const bf16_t* Bz = B + (long)n0 * 768;

    const int tid  = threadIdx.x;
    const int lane = tid & 63;
    const int wn   = (tid >> 6) * 32;
    const int l15  = lane & 15;
    const int quad = lane >> 4;

    const f32x4 fz = {0.f, 0.f, 0.f, 0.f};
    f32x4 acc[4][2];
#pragma unroll
    for (int i = 0; i < 4; ++i)
#pragma unroll
        for (int j = 0; j < 2; ++j) acc[i][j] = fz;

    kloop64(Az, Bz, 768, 768, 768, tid, As, Bs, wn, l15, quad, acc);

#pragma unroll
    for (int i = 0; i < 4; ++i) {
#pragma unroll
        for (int j = 0; j < 2; ++j) {
            const int mb = m0 + i * 16 + quad * 4;
            const int nc = n0 + wn + j * 16 + l15;
#pragma unroll
            for (int r = 0; r < 4; ++r)
                C[(long)(mb + r) * 768 + nc] = (bf16_t)(acc[i][j][r] + ldv(bias, nc, bmode));
        }
    }
}

// ---------------------------------------------------------------- VT GEMM (128e x 128m, acc[4][4])
// VTcat[b][e][hc*1024+m] = sum_k ynb[b,m][k] * W2T[e][(h0+hc)*768+k]   (= (yn@wv_h)^T)
// grid (8, 48, G) = 1536 blocks at G=4 -> 5 blocks/CU (32 KB LDS), 20 waves/CU;
// b = blockIdx.x (XCD<->batch affinity). e0 = (y/8)*128 (6), mc0 = (y&7)*128 (8).
__global__ __launch_bounds__(256)
void gemm_vt(const bf16_t* __restrict__ W2T, const bf16_t* __restrict__ ynb,
             bf16_t* __restrict__ VTc, int h0, int ldP) {
    __shared__ char As[128 * 128];
    __shared__ char Bs[128 * 128];
    const int b   = blockIdx.x;
    const int hc  = blockIdx.z;
    const int e0  = (blockIdx.y >> 3) * 128;
    const int mc0 = (blockIdx.y & 7) * 128;
    const bf16_t* Az = W2T + (long)e0 * 9216 + (h0 + hc) * 768;
    const bf16_t* Bz = ynb + ((long)b * 1024 + mc0) * 768;

    const int tid  = threadIdx.x;
    const int lane = tid & 63;
    const int w    = tid >> 6;
    const int wm   = (w >> 1) * 64;
    const int wn   = (w & 1) * 64;
    const int l15  = lane & 15;
    const int quad = lane >> 4;

    const f32x4 fz = {0.f, 0.f, 0.f, 0.f};
    f32x4 acc[4][4];
#pragma unroll
    for (int i = 0; i < 4; ++i)
#pragma unroll
        for (int j = 0; j < 4; ++j) acc[i][j] = fz;

    kloop128(Az, Bz, 768, 9216, 768, tid, As, Bs, wm, wn, l15, quad, acc);

    bf16_t* C = VTc + (long)b * 768 * ldP + (long)hc * 1024;
#pragma unroll
    for (int i = 0; i < 4; ++i) {
#pragma unroll
        for (int j = 0; j < 4; ++j) {
            const int er = e0 + wm + i * 16 + quad * 4;
            const int mc = mc0 + wn + j * 16 + l15;
#pragma unroll
            for (int r = 0; r < 4; ++r)
                C[(long)(er + r) * ldP + mc] = (bf16_t)acc[i][j][r];
        }
    }
}

// ---------------------------------------------------------------- dx GEMM (128x128, acc[4][4], split-K x2)
// dx_b = Pcat_b @ VTcat_b^T. grid (8, 48, 2) = 768 blocks = 3/CU = 12 waves/CU
// (the m97 regime). z = K-split half; each half accumulates into its OWN f32
// buffer dxf + z*6291456 (race-free, no atomics); hpre_ep combines at the end.
// first=1 on pass 0 (write), else read-modify-write across passes.
__global__ __launch_bounds__(256)
void gemm_dx(const bf16_t* __restrict__ P, const bf16_t* __restrict__ VTc,
             float* __restrict__ dxf, int KH, int ldP, int first) {
    __shared__ char As[128 * 128];
    __shared__ char Bs[128 * 128];
    const int b  = blockIdx.x;
    const int t  = blockIdx.y;
    const int ks = blockIdx.z;
    const int m0 = (t / 6) * 128;     // 8 m-tiles
    const int n0 = (t % 6) * 128;     // 6 n-tiles
    const bf16_t* Az = P   + ((long)b * 1024 + m0) * ldP + ks * KH;
    const bf16_t* Bz = VTc + ((long)b * 768  + n0) * ldP + ks * KH;
    float* dxs = dxf + (long)ks * 6291456;

    const int tid  = threadIdx.x;
    const int lane = tid & 63;
    const int w    = tid >> 6;
    const int wm   = (w >> 1) * 64;
    const int wn   = (w & 1) * 64;
    const int l15  = lane & 15;
    const int quad = lane >> 4;

    const f32x4 fz = {0.f, 0.f, 0.f, 0.f};
    f32x4 acc[4][4];
#pragma unroll
    for (int i = 0; i < 4; ++i)
#pragma unroll
        for (int j = 0; j < 4; ++j) acc[i][j] = fz;

    kloop128(Az, Bz, KH, ldP, ldP, tid, As, Bs, wm, wn, l15, quad, acc);

#pragma unroll
    for (int i = 0; i < 4; ++i) {
#pragma unroll
        for (int j = 0; j < 4; ++j) {
            const int gr = b * 1024 + m0 + wm + i * 16 + quad * 4;
            const int nc = n0 + wn + j * 16 + l15;
#pragma unroll
            for (int r = 0; r < 4; ++r) {
                const long gi = (long)(gr + r) * 768 + nc;
                float v = acc[i][j][r];
                if (!first) v += dxs[gi];
                dxs[gi] = v;
            }
        }
    }
}

// ---------------------------------------------------------------- h_pre epilogue (combines K-splits)
__global__ __launch_bounds__(256)
void hpre_ep(const float* __restrict__ dxf, const float* __restrict__ bvs,
             const bf16_t* __restrict__ xn, bf16_t* __restrict__ hp) {
    const long i = (long)blockIdx.x * 256 + threadIdx.x;   // grid covers 6291456
    const int e = (int)(i % 768);
    hp[i] = (bf16_t)(dxf[i] + dxf[i + 6291456] + bvs[e] + (float)xn[i]);
}

// ---------------------------------------------------------------- fused S -> softmax -> P (cat layout)
// Per (b, 16-row n-tile, head hc of this pass): S = Q K^T / 8 (full M=1024 in
// regs; 8 col-waves), exact softmax, P -> LDS -> coalesced store to
// Pcat[b*1024+n][hc*1024+m], pitch ldP. Grid x = 512*G; b = bx&7 (XCD affinity).
__global__ __launch_bounds__(512, 8)
void fused_S(const bf16_t* __restrict__ Q, const bf16_t* __restrict__ Kp,
             bf16_t* __restrict__ P, int h0, int ldP) {
    __shared__ bf16_t Pl[16][1032];
    __shared__ float  rmax[8][16];
    __shared__ float  rsum[8][16];

    const int bx   = blockIdx.x;
    const int b    = bx & 7;
    const int n0   = ((bx >> 3) & 63) * 16;
    const int hc   = bx >> 9;           // head within pass
    const int h    = h0 + hc;           // global head
    const int tid  = threadIdx.x;
    const int w    = tid >> 6;          // 0..7 col-waves
    const int lane = tid & 63;
    const int l15  = lane & 15;
    const int quad = lane >> 4;

    const f32x4 fz = {0.f, 0.f, 0.f, 0.f};
    const long qoff = (long)(b * 1024 + n0 + l15) * 768 + h * 64 + quad * 8;
    const long koff = (long)(b * 1024) * 768 + h * 64 + quad * 8;

    // ---- S = Q K^T: this wave covers cols m = w*128 + f*16 + l15
    f32x4 s[8];
#pragma unroll
    for (int f = 0; f < 8; ++f) s[f] = fz;
    const bf16x8 qa0 = *(const bf16x8*)(Q + qoff);
    const bf16x8 qa1 = *(const bf16x8*)(Q + qoff + 32);
#pragma unroll
    for (int f = 0; f < 8; ++f) {
        const int m = w * 128 + f * 16 + l15;
        const bf16_t* kp = Kp + koff + (long)m * 768;
        s[f] = mfma16(qa0, *(const bf16x8*)kp, s[f]);
        s[f] = mfma16(qa1, *(const bf16x8*)(kp + 32), s[f]);
    }
    // ---- softmax over m; lane owns rows quad*4 + r
    float rm[4] = {-3e38f, -3e38f, -3e38f, -3e38f};
#pragma unroll
    for (int f = 0; f < 8; ++f)
#pragma unroll
        for (int r = 0; r < 4; ++r) {
            s[f][r] *= 0.125f;
            rm[r] = fmaxf(rm[r], s[f][r]);
        }
#pragma unroll
    for (int off = 1; off < 16; off <<= 1)
#pragma unroll
        for (int r = 0; r < 4; ++r) rm[r] = fmaxf(rm[r], __shfl_xor(rm[r], off));
    if (l15 == 0) {
#pragma unroll
        for (int r = 0; r < 4; ++r) rmax[w][quad * 4 + r] = rm[r];
    }
    __syncthreads();
    float gm[4];
#pragma unroll
    for (int r = 0; r < 4; ++r) {
        float mx = rmax[0][quad * 4 + r];
#pragma unroll
        for (int w2 = 1; w2 < 8; ++w2) mx = fmaxf(mx, rmax[w2][quad * 4 + r]);
        gm[r] = mx;
    }
    float ps[4] = {0.f, 0.f, 0.f, 0.f};
#pragma unroll
    for (int f = 0; f < 8; ++f)
#pragma unroll
        for (int r = 0; r < 4; ++r) {
            const float p = __expf(s[f][r] - gm[r]);
            s[f][r] = p;
            ps[r] += p;
        }
#pragma unroll
    for (int off = 1; off < 16; off <<= 1)
#pragma unroll
        for (int r = 0; r < 4; ++r) ps[r] += __shfl_xor(ps[r], off);
    if (l15 == 0) {
#pragma unroll
        for (int r = 0; r < 4; ++r) rsum[w][quad * 4 + r] = ps[r];
    }
    __syncthreads();
#pragma unroll
    for (int r = 0; r < 4; ++r) {
        float ss = 0.f;
#pragma unroll
        for (int w2 = 0; w2 < 8; ++w2) ss += rsum[w2][quad * 4 + r];
        gm[r] = 1.0f / ss;
    }
#pragma unroll
    for (int f = 0; f < 8; ++f)
#pragma unroll
        for (int r = 0; r < 4; ++r)
            Pl[quad * 4 + r][w * 128 + f * 16 + l15] = (bf16_t)(s[f][r] * gm[r]);
    __syncthreads();

    // ---- coalesced store of the 16x1024 P tile (32 threads per row)
    const long pbase = ((long)b * 1024 + n0) * ldP + (long)hc * 1024;
    const int rr = tid >> 5;
    const int c0 = (tid & 31) * 32;
    bf16_t* dst = P + pbase + (long)rr * ldP + c0;
#pragma unroll
    for (int u = 0; u < 4; ++u)
        *(bf16x8*)(dst + u * 8) = *(const bf16x8*)(&Pl[rr][c0 + u * 8]);
}

// ---------------------------------------------------------------- output emit
__global__ __launch_bounds__(256)
void emit2(const bf16_t* __restrict__ a, const bf16_t* __restrict__ b,
           void* __restrict__ out, const int* __restrict__ flagp) {
    const int mode = *flagp;
    const long n = 6291456;
    const long stride = (long)gridDim.x * blockDim.x;
    for (long i = (long)blockIdx.x * blockDim.x + threadIdx.x; i < 2 * n; i += stride) {
        const bf16_t v = (i < n) ? a[i] : b[i - n];
        if (mode) ((float*)out)[i] = (float)v;
        else      ((bf16_t*)out)[i] = v;
    }
}

// ---------------------------------------------------------------- launch
extern "C" void kernel_launch(void* const* d_in, const int* in_sizes, int n_in,
                              void* d_out, int out_size, void* d_ws, size_t ws_size,
                              hipStream_t stream) {
    (void)in_sizes; (void)n_in; (void)out_size;

    const void* x    = d_in[0];
    const void* y    = d_in[1];
    const void* ln1g = d_in[2];
    const void* ln1b = d_in[3];
    const void* ln2g = d_in[4];
    const void* ln2b = d_in[5];
    const void* ln3g = d_in[6];
    const void* ln3b = d_in[7];
    const void* wq   = d_in[8];
    const void* bq   = d_in[9];
    const void* wk   = d_in[10];
    const void* bk   = d_in[11];
    const void* wv   = d_in[12];
    const void* bv   = d_in[13];
    const void* wi   = d_in[14];
    const void* bi   = d_in[15];
    const void* wo   = d_in[16];
    const void* bo   = d_in[17];

    // ---- workspace layout (canonical bf16 unless noted) ----
    // fixed block ends at 69,214,208; dxf = 2 x 25,165,824 (split-K halves);
    // Pcat/VTc at 119,545,856: need = 121,380,864 + G*29,360,128.
    // G=3 floor (209.5 MB) < the >=213.7 MB proven present in r3-r8 (G=4 ran).
    char* ws = (char*)d_ws;
    bf16_t* xn    = (bf16_t*)(ws + 0);           // 12,582,912 (later res0)
    bf16_t* ynb   = (bf16_t*)(ws + 12582912);    // 12,582,912 (output 1)
    bf16_t* qb    = (bf16_t*)(ws + 25165824);    // 12,582,912 (Q; later h_pre)
    bf16_t* kb    = (bf16_t*)(ws + 37748736);    // 12,582,912 (K; later hn)
    bf16_t* W2T   = (bf16_t*)(ws + 50331648);    // 14,155,776
    bf16_t* wqT   = (bf16_t*)(ws + 64487424);    // 1,179,648
    bf16_t* wkT   = (bf16_t*)(ws + 65667072);
    bf16_t* wiT   = (bf16_t*)(ws + 66846720);
    bf16_t* woT   = (bf16_t*)(ws + 68026368);
    float*  bvs   = (float*) (ws + 69206016);    // 3,072
    int*    flag  = (int*)   (ws + 69210112);    // flag[0]=fp32 mode, flag[1]=0
    float*  dxf   = (float*) (ws + 69214208);    // 50,331,648 (2 split-K halves)

    static const int GS[5] = {12, 6, 4, 3, 2};
    int G = 2;
    for (int i = 0; i < 5; ++i) {
        const unsigned long long need =
            121380864ULL + (unsigned long long)GS[i] * 29360128ULL;
        if (need <= (unsigned long long)ws_size) { G = GS[i]; break; }
    }
    const int KK  = G * 1024;
    const int ldP = KK + 64;
    bf16_t* Pcat = (bf16_t*)(ws + 119545856);                // 8192 x ldP
    bf16_t* VTc  = Pcat + (size_t)8192 * ldP;                // 6144 x ldP
    bf16_t* hpre = qb;
    bf16_t* hn   = kb;
    bf16_t* mid  = Pcat;     // 12.6 MB, reused after attention
    bf16_t* res0 = xn;
    const int* F = flag;
    const int* Z = flag + 1;

    detect_dtype<<<1, 256, 0, stream>>>(x, flag);

    const dim3 tb(32, 8);
    transpose_cvt<<<dim3(24, 24, 1), tb, 0, stream>>>(wq, wqT, 768, 768, F);
    transpose_cvt<<<dim3(24, 24, 1), tb, 0, stream>>>(wk, wkT, 768, 768, F);
    transpose_cvt<<<dim3(24, 24, 1), tb, 0, stream>>>(wi, wiT, 768, 768, F);
    transpose_cvt<<<dim3(24, 24, 1), tb, 0, stream>>>(wo, woT, 768, 768, F);
    transpose_wv<<<dim3(24, 24, 12), tb, 0, stream>>>(wv, W2T, F);
    bvsum_k<<<3, 256, 0, stream>>>(bv, bvs, F);

    ln768<<<8192, 256, 0, stream>>>(x, xn, ln1g, ln1b, F, F);
    ln768<<<8192, 256, 0, stream>>>(y, ynb, ln2g, ln2b, F, F);

    // Q = xn @ wq + bq; K = yn @ wk + bk  (1536 blocks of 64x128)
    gemm_qk<<<dim3(6, 128, 2), 256, 0, stream>>>(xn, ynb, wqT, wkT, qb, kb, bq, bk, F);

    // attention middle, cat-K route:
    //   Pcat[b][n][hc*1024+m] = softmax(Q K^T / 8)
    //   VTcat[b][e][hc*1024+m] = (yn @ wv_h)^T   (128^2 tiles, 1536 blocks)
    //   dxf[z] (+)= Pcat_b @ VTcat_b^T  (128^2 tiles + split-K x2, 768 blocks)
    const int npass = 12 / G;
    for (int p = 0; p < npass; ++p) {
        const int h0 = p * G;
        fused_S<<<512 * G, 512, 0, stream>>>(qb, kb, Pcat, h0, ldP);
        gemm_vt<<<dim3(8, 48, G), 256, 0, stream>>>(W2T, ynb, VTc, h0, ldP);
        gemm_dx<<<dim3(8, 48, 2), 256, 0, stream>>>(Pcat, VTc, dxf, KK / 2, ldP,
                                                    p == 0);
    }

    // h_pre = xn + dxf0 + dxf1 + sum_h bv_h   (qb dead -> reuse)
    hpre_ep<<<24576, 256, 0, stream>>>(dxf, bvs, xn, hpre);

    ln768<<<8192, 256, 0, stream>>>(hpre, hn, ln3g, ln3b, Z, F);

    gemm_bt<<<dim3(6, 128), 256, 0, stream>>>(hn, wiT, mid, 768, 768, 768, 768,
                                              bi, F, nullptr, 1);
    gemm_bt<<<dim3(6, 128), 256, 0, stream>>>(mid, woT, res0, 768, 768, 768, 768,
                                              bo, F, hn, 0);

    emit2<<<2048, 256, 0, stream>>>(res0, ynb, d_out, F);
}

// Round 11
// 823.257 us; speedup vs baseline: 1.1772x; 1.1772x over previous
//
#include <hip/hip_runtime.h>
#include <hip/hip_bf16.h>
#include <stdint.h>

// Inputs may be float32 OR bf16 (detected at runtime on-device); internal
// canonical dtype is bf16; compute in fp32; output emitted in detected dtype.
typedef __bf16 bf16_t;
typedef __bf16 bf16x8 __attribute__((ext_vector_type(8)));
typedef float  f32x4  __attribute__((ext_vector_type(4)));

typedef __attribute__((address_space(3))) unsigned int lds_u32;
typedef const __attribute__((address_space(1))) unsigned int glob_u32;
#define GLDS16(g, l) __builtin_amdgcn_global_load_lds((glob_u32*)(g), (lds_u32*)(l), 16, 0, 0)

__device__ __forceinline__ f32x4 mfma16(bf16x8 a, bf16x8 b, f32x4 c) {
    // D[row=quad*4+r][col=lane&15]; A[row=lane&15][k=quad*8+j]; B[k=quad*8+j][col=lane&15]
    return __builtin_amdgcn_mfma_f32_16x16x32_bf16(a, b, c, 0, 0, 0);
}

__device__ __forceinline__ float ldv(const void* p, long i, int fp32mode) {
    return fp32mode ? ((const float*)p)[i] : (float)((const bf16_t*)p)[i];
}

// ---------------------------------------------------------------- dtype detect
__global__ __launch_bounds__(256)
void detect_dtype(const void* __restrict__ x, int* __restrict__ flag) {
    __shared__ int cnt;
    if (threadIdx.x == 0) cnt = 0;
    __syncthreads();
    const bf16_t* p = (const bf16_t*)x;
    int local = 0;
    for (int i = threadIdx.x; i < 4096; i += 256) {
        const float v = (float)p[i];
        if (!(fabsf(v) < 1e6f)) local++;   // catches NaN too
    }
    atomicAdd(&cnt, local);
    __syncthreads();
    if (threadIdx.x == 0) { flag[0] = (cnt >= 16) ? 1 : 0; flag[1] = 0; }
}

// ---------------------------------------------------------------- 4 weight transposes in one dispatch
// z selects the (in,out) pair; all are 768x768.
__global__ __launch_bounds__(256)
void transpose_w4(const void* __restrict__ i0, const void* __restrict__ i1,
                  const void* __restrict__ i2, const void* __restrict__ i3,
                  bf16_t* __restrict__ o0, bf16_t* __restrict__ o1,
                  bf16_t* __restrict__ o2, bf16_t* __restrict__ o3,
                  const int* __restrict__ flagp) {
    __shared__ bf16_t t[32][33];
    const int mode = *flagp;
    const int z = blockIdx.z;
    const void* in = (z == 0) ? i0 : (z == 1) ? i1 : (z == 2) ? i2 : i3;
    bf16_t*    out = (z == 0) ? o0 : (z == 1) ? o1 : (z == 2) ? o2 : o3;
    const int c0 = blockIdx.x * 32;
    const int r0 = blockIdx.y * 32;
    const int x  = threadIdx.x & 31;
    const int y0 = threadIdx.x >> 5;
    for (int yy = y0; yy < 32; yy += 8)
        t[yy][x] = (bf16_t)ldv(in, (long)(r0 + yy) * 768 + c0 + x, mode);
    __syncthreads();
    for (int yy = y0; yy < 32; yy += 8)
        out[(long)(c0 + yy) * 768 + r0 + x] = t[x][yy];
}

// ---------------------------------------------------------------- wv permuted transpose
// W2T[e][h*768+k] = wv[k][h*768+e]   (both ld 9216)
__global__ __launch_bounds__(256)
void transpose_wv(const void* __restrict__ in, bf16_t* __restrict__ out,
                  const int* __restrict__ flagp) {
    __shared__ bf16_t t[32][33];
    const int mode = *flagp;
    const int h  = blockIdx.z;
    const int e0 = blockIdx.x * 32;
    const int k0 = blockIdx.y * 32;
    const int x  = threadIdx.x;
    const int y0 = threadIdx.y;
    for (int yy = y0; yy < 32; yy += 8)
        t[yy][x] = (bf16_t)ldv(in, (long)(k0 + yy) * 9216 + h * 768 + e0 + x, mode);
    __syncthreads();
    for (int yy = y0; yy < 32; yy += 8)
        out[(long)(e0 + yy) * 9216 + h * 768 + k0 + x] = t[x][yy];
}

// ---------------------------------------------------------------- bv head-sum
__global__ __launch_bounds__(256)
void bvsum_k(const void* __restrict__ bv, float* __restrict__ out,
             const int* __restrict__ flagp) {
    const int mode = *flagp;
    const int e = blockIdx.x * 256 + threadIdx.x;
    if (e < 768) {
        float s = 0.f;
#pragma unroll
        for (int h = 0; h < 12; ++h) s += ldv(bv, h * 768 + e, mode);
        out[e] = s;
    }
}

// ---------------------------------------------------------------- merged layernorm for x and y
// Rows 0..8191 -> xn (ln1); rows 8192..16383 -> ynb (ln2) AND direct emit of
// output 1 (yn) to d_out+n in the detected dtype (replaces half of emit2).
__global__ __launch_bounds__(256)
void ln_xy(const void* __restrict__ x, const void* __restrict__ y,
           bf16_t* __restrict__ xn, bf16_t* __restrict__ ynb,
           const void* __restrict__ g1, const void* __restrict__ b1,
           const void* __restrict__ g2, const void* __restrict__ b2,
           void* __restrict__ outp, const int* __restrict__ flagp) {
    __shared__ float rs[256], rq[256];
    const int mode = *flagp;
    const int ri   = blockIdx.x;
    const int isy  = ri >> 13;                 // 0: x-half, 1: y-half
    const long rr  = ri & 8191;
    const void* in = isy ? y : x;
    const void* gam = isy ? g2 : g1;
    const void* bet = isy ? b2 : b1;
    const long base = rr * 768;
    const int tid = threadIdx.x;
    float v[3];
    float s = 0.f, q = 0.f;
#pragma unroll
    for (int i = 0; i < 3; ++i) {
        v[i] = ldv(in, base + i * 256 + tid, mode);
        s += v[i];
        q += v[i] * v[i];
    }
    rs[tid] = s; rq[tid] = q;
    __syncthreads();
    for (int st = 128; st > 0; st >>= 1) {
        if (tid < st) { rs[tid] += rs[tid + st]; rq[tid] += rq[tid + st]; }
        __syncthreads();
    }
    const float mean = rs[0] * (1.0f / 768.0f);
    const float var  = rq[0] * (1.0f / 768.0f) - mean * mean;
    const float rstd = rsqrtf(var + 1e-5f);
    bf16_t* dst = isy ? ynb : xn;
#pragma unroll
    for (int i = 0; i < 3; ++i) {
        const int c = i * 256 + tid;
        const float o = (v[i] - mean) * rstd * ldv(gam, c, mode) + ldv(bet, c, mode);
        const bf16_t ob = (bf16_t)o;
        dst[base + c] = ob;
        if (isy) {   // output 1 = yn at d_out + 6291456
            const long oi = 6291456 + base + c;
            if (mode) ((float*)outp)[oi] = (float)ob;
            else      ((bf16_t*)outp)[oi] = ob;
        }
    }
}

// ---------------------------------------------------------------- layernorm (768 cols) for hn
__global__ __launch_bounds__(256)
void ln768(const void* __restrict__ in, bf16_t* __restrict__ out,
           const void* __restrict__ gam, const void* __restrict__ bet,
           const int* __restrict__ dmodep, const int* __restrict__ pmodep) {
    __shared__ float rs[256], rq[256];
    const int dm = *dmodep, pm = *pmodep;
    const long base = (long)blockIdx.x * 768;
    const int tid = threadIdx.x;
    float v[3];
    float s = 0.f, q = 0.f;
#pragma unroll
    for (int i = 0; i < 3; ++i) {
        v[i] = ldv(in, base + i * 256 + tid, dm);
        s += v[i];
        q += v[i] * v[i];
    }
    rs[tid] = s; rq[tid] = q;
    __syncthreads();
    for (int st = 128; st > 0; st >>= 1) {
        if (tid < st) { rs[tid] += rs[tid + st]; rq[tid] += rq[tid + st]; }
        __syncthreads();
    }
    const float mean = rs[0] * (1.0f / 768.0f);
    const float var  = rq[0] * (1.0f / 768.0f) - mean * mean;
    const float rstd = rsqrtf(var + 1e-5f);
#pragma unroll
    for (int i = 0; i < 3; ++i) {
        const int c = i * 256 + tid;
        out[base + c] = (bf16_t)((v[i] - mean) * rstd * ldv(gam, c, pm) + ldv(bet, c, pm));
    }
}

// ================================================================ GEMM engine
// r8-proven config (measured 842 us total; gemm_dx 87 us = 592 TF): 64(m) x
// 128(n) tile, BK=64, 256 threads / 4 waves (each 64m x 32n, acc[4][2]).
// global_load_lds width-16 into LINEAR LDS (24,576 B), SINGLE buffer, 2
// barriers/K-step, both-sides XOR swizzle -> zero bank conflicts (r8 PMC).
// REFUTED alternatives (keep for the record): kloop128 acc[4][4] + split-K
// (r10: 442 TF, -125 us total); reg-staging pad-72 (r7: 9.4M write conflicts);
// explicit dbuf (r2-r4); 8-wave tiles (r4); pitch padding (r6: neutral).
__device__ __forceinline__ void kloop64(const bf16_t* Az, const bf16_t* Bz,
                                        int K, int lda, int ldb, int tid,
                                        char* As, char* Bs,
                                        int wn, int l15, int quad,
                                        f32x4 (&acc)[4][2]) {
    const int srow = tid >> 3;                               // 0..31
    const int sc   = ((tid & 7) * 16) ^ ((srow & 7) << 4);   // pre-swizzled src col
    char* lA = As + (tid >> 6) * 1024;   // wave-uniform dest base (+lane*16 by HW)
    char* lB = Bs + (tid >> 6) * 1024;
    const int rsw = (l15 & 7) << 4;      // read-side XOR
    for (int k0 = 0; k0 < K; k0 += 64) {
        __syncthreads();
        GLDS16((const char*)(Az + (long)srow * lda + k0) + sc, lA);
        GLDS16((const char*)(Az + (long)(srow + 32) * lda + k0) + sc, lA + 4096);
#pragma unroll
        for (int p = 0; p < 4; ++p)
            GLDS16((const char*)(Bz + (long)(srow + p * 32) * ldb + k0) + sc, lB + p * 4096);
        __syncthreads();   // compiler drains vmcnt(0) here (m97 pattern)
#pragma unroll
        for (int kk = 0; kk < 64; kk += 32) {
            bf16x8 af[4], bfr[2];
            const int cb = kk * 2 + quad * 16;
#pragma unroll
            for (int i = 0; i < 4; ++i)
                af[i] = *(const bf16x8*)(As + (i * 16 + l15) * 128 + (cb ^ rsw));
#pragma unroll
            for (int j = 0; j < 2; ++j)
                bfr[j] = *(const bf16x8*)(Bs + (wn + j * 16 + l15) * 128 + (cb ^ rsw));
#pragma unroll
            for (int i = 0; i < 4; ++i)
#pragma unroll
                for (int j = 0; j < 2; ++j)
                    acc[i][j] = mfma16(af[i], bfr[j], acc[i][j]);
        }
    }
}

// bijective XCD chunk swizzle over nwg blocks (nwg % 8 == 0)
__device__ __forceinline__ int xcd_swz(int lin, int nwg) {
    return (lin & 7) * (nwg >> 3) + (lin >> 3);
}

// ---------------------------------------------------------------- generic GEMM C = A*B^T
// 64x128 tiles; grid (6, 128) = 768 blocks = 3/CU. If eout != null, the
// result (bias/relu/res applied) is written to eout in the detected dtype
// (fused output emit -> replaces emit2 for output 0); else bf16 to C.
__global__ __launch_bounds__(256)
void gemm_bt(const bf16_t* __restrict__ A, const bf16_t* __restrict__ B,
             bf16_t* __restrict__ C,
             int K, int lda, int ldb, int ldc,
             const void* __restrict__ bias, const int* __restrict__ flagp,
             const bf16_t* __restrict__ res, int do_relu,
             void* __restrict__ eout) {
    __shared__ char As[64 * 128];
    __shared__ char Bs[128 * 128];
    const int bmode = *flagp;
    const int swz = xcd_swz(blockIdx.y * 6 + blockIdx.x, 768);
    const int n0 = (swz % 6) * 128;
    const int m0 = (swz / 6) * 64;
    const bf16_t* Az = A + (long)m0 * lda;
    const bf16_t* Bz = B + (long)n0 * ldb;

    const int tid  = threadIdx.x;
    const int lane = tid & 63;
    const int wn   = (tid >> 6) * 32;
    const int l15  = lane & 15;
    const int quad = lane >> 4;

    const f32x4 fz = {0.f, 0.f, 0.f, 0.f};
    f32x4 acc[4][2];
#pragma unroll
    for (int i = 0; i < 4; ++i)
#pragma unroll
        for (int j = 0; j < 2; ++j) acc[i][j] = fz;

    kloop64(Az, Bz, K, lda, ldb, tid, As, Bs, wn, l15, quad, acc);

#pragma unroll
    for (int i = 0; i < 4; ++i) {
#pragma unroll
        for (int j = 0; j < 2; ++j) {
            const int mb = m0 + i * 16 + quad * 4;
            const int nc = n0 + wn + j * 16 + l15;
#pragma unroll
            for (int r = 0; r < 4; ++r) {
                float v = acc[i][j][r];
                if (bias) v += ldv(bias, nc, bmode);
                if (do_relu) v = fmaxf(v, 0.0f);
                if (res) v += (float)res[(long)(mb + r) * ldc + nc];
                const long gi = (long)(mb + r) * ldc + nc;
                if (eout) {
                    if (bmode) ((float*)eout)[gi] = v;
                    else       ((bf16_t*)eout)[gi] = (bf16_t)v;
                } else {
                    C[gi] = (bf16_t)v;
                }
            }
        }
    }
}

// ---------------------------------------------------------------- merged Q/K projection (64x128)
__global__ __launch_bounds__(256)
void gemm_qk(const bf16_t* __restrict__ xn, const bf16_t* __restrict__ ynb,
             const bf16_t* __restrict__ wqT, const bf16_t* __restrict__ wkT,
             bf16_t* __restrict__ qb, bf16_t* __restrict__ kb,
             const void* __restrict__ bq, const void* __restrict__ bk,
             const int* __restrict__ flagp) {
    __shared__ char As[64 * 128];
    __shared__ char Bs[128 * 128];
    const int bmode = *flagp;
    const int z = blockIdx.z;
    const bf16_t* A = z ? ynb : xn;
    const bf16_t* B = z ? wkT : wqT;
    bf16_t*       C = z ? kb  : qb;
    const void* bias = z ? bk : bq;
    const int swz = xcd_swz(blockIdx.y * 6 + blockIdx.x, 768);
    const int n0 = (swz % 6) * 128;
    const int m0 = (swz / 6) * 64;
    const bf16_t* Az = A + (long)m0 * 768;
    const bf16_t* Bz = B + (long)n0 * 768;

    const int tid  = threadIdx.x;
    const int lane = tid & 63;
    const int wn   = (tid >> 6) * 32;
    const int l15  = lane & 15;
    const int quad = lane >> 4;

    const f32x4 fz = {0.f, 0.f, 0.f, 0.f};
    f32x4 acc[4][2];
#pragma unroll
    for (int i = 0; i < 4; ++i)
#pragma unroll
        for (int j = 0; j < 2; ++j) acc[i][j] = fz;

    kloop64(Az, Bz, 768, 768, 768, tid, As, Bs, wn, l15, quad, acc);

#pragma unroll
    for (int i = 0; i < 4; ++i) {
#pragma unroll
        for (int j = 0; j < 2; ++j) {
            const int mb = m0 + i * 16 + quad * 4;
            const int nc = n0 + wn + j * 16 + l15;
#pragma unroll
            for (int r = 0; r < 4; ++r)
                C[(long)(mb + r) * 768 + nc] = (bf16_t)(acc[i][j][r] + ldv(bias, nc, bmode));
        }
    }
}

// ---------------------------------------------------------------- VT GEMM (64e x 128m)
// VTcat[b][e][hc*1024+m] = sum_k ynb[b,m][k] * W2T[e][(h0+hc)*768+k]   (= (yn@wv_h)^T)
// grid (8, 96, G): b = blockIdx.x (XCD<->batch affinity; linear%8 == x),
// e0 = (y>>3)*64, mc0 = (y&7)*128.
__global__ __launch_bounds__(256)
void gemm_vt(const bf16_t* __restrict__ W2T, const bf16_t* __restrict__ ynb,
             bf16_t* __restrict__ VTc, int h0, int ldP) {
    __shared__ char As[64 * 128];
    __shared__ char Bs[128 * 128];
    const int b   = blockIdx.x;
    const int hc  = blockIdx.z;
    const int e0  = (blockIdx.y >> 3) * 64;
    const int mc0 = (blockIdx.y & 7) * 128;
    const bf16_t* Az = W2T + (long)e0 * 9216 + (h0 + hc) * 768;
    const bf16_t* Bz = ynb + ((long)b * 1024 + mc0) * 768;

    const int tid  = threadIdx.x;
    const int lane = tid & 63;
    const int wn   = (tid >> 6) * 32;
    const int l15  = lane & 15;
    const int quad = lane >> 4;

    const f32x4 fz = {0.f, 0.f, 0.f, 0.f};
    f32x4 acc[4][2];
#pragma unroll
    for (int i = 0; i < 4; ++i)
#pragma unroll
        for (int j = 0; j < 2; ++j) acc[i][j] = fz;

    kloop64(Az, Bz, 768, 9216, 768, tid, As, Bs, wn, l15, quad, acc);

    bf16_t* C = VTc + (long)b * 768 * ldP + (long)hc * 1024;
#pragma unroll
    for (int i = 0; i < 4; ++i) {
#pragma unroll
        for (int j = 0; j < 2; ++j) {
            const int er = e0 + i * 16 + quad * 4;
            const int mc = mc0 + wn + j * 16 + l15;
#pragma unroll
            for (int r = 0; r < 4; ++r)
                C[(long)(er + r) * ldP + mc] = (bf16_t)acc[i][j][r];
        }
    }
}

// ---------------------------------------------------------------- dx GEMM (64x128), K = KK = G*1024
// dx_b = Pcat_b @ VTcat_b^T; epilogue fuses + dxf(prev passes) + xn + bvs -> hpre.
// mode: 0 first(write dxf), 1 mid(dxf+=), 2 last(hp=dxf+acc+xn+bvs), 3 only(hp=acc+xn+bvs)
// grid (8, 96) = 768 blocks = 3 blocks/CU (12 waves/CU), one exact round;
// b = blockIdx.x (XCD<->batch affinity).
__global__ __launch_bounds__(256)
void gemm_dx(const bf16_t* __restrict__ P, const bf16_t* __restrict__ VTc,
             float* __restrict__ dxf, const bf16_t* __restrict__ xnb,
             const float* __restrict__ bvs, bf16_t* __restrict__ hp,
             int KK, int ldP, int mode) {
    __shared__ char As[64 * 128];
    __shared__ char Bs[128 * 128];
    const int b  = blockIdx.x;
    const int t  = blockIdx.y;
    const int m0 = (t / 6) * 64;      // n-rows (16 tiles)
    const int n0 = (t % 6) * 128;     // e-cols (6 tiles)
    const bf16_t* Az = P   + ((long)b * 1024 + m0) * ldP;
    const bf16_t* Bz = VTc + ((long)b * 768  + n0) * ldP;

    const int tid  = threadIdx.x;
    const int lane = tid & 63;
    const int wn   = (tid >> 6) * 32;
    const int l15  = lane & 15;
    const int quad = lane >> 4;

    const f32x4 fz = {0.f, 0.f, 0.f, 0.f};
    f32x4 acc[4][2];
#pragma unroll
    for (int i = 0; i < 4; ++i)
#pragma unroll
        for (int j = 0; j < 2; ++j) acc[i][j] = fz;

    kloop64(Az, Bz, KK, ldP, ldP, tid, As, Bs, wn, l15, quad, acc);

#pragma unroll
    for (int i = 0; i < 4; ++i) {
#pragma unroll
        for (int j = 0; j < 2; ++j) {
            const int gr = b * 1024 + m0 + i * 16 + quad * 4;
            const int nc = n0 + wn + j * 16 + l15;
#pragma unroll
            for (int r = 0; r < 4; ++r) {
                const long gi = (long)(gr + r) * 768 + nc;
                float v = acc[i][j][r];
                if (mode == 1 || mode == 2) v += dxf[gi];
                if (mode <= 1) dxf[gi] = v;
                else hp[gi] = (bf16_t)(v + bvs[nc] + (float)xnb[gi]);
            }
        }
    }
}

// ---------------------------------------------------------------- fused S -> softmax -> P (cat layout)
// Per (b, 16-row n-tile, head hc of this pass): S = Q K^T / 8 (full M=1024 in
// regs; 8 col-waves), exact softmax, P -> LDS -> coalesced store to
// Pcat[b*1024+n][hc*1024+m], pitch ldP. Grid x = 512*G; b = bx&7 (XCD affinity).
__global__ __launch_bounds__(512, 8)
void fused_S(const bf16_t* __restrict__ Q, const bf16_t* __restrict__ Kp,
             bf16_t* __restrict__ P, int h0, int ldP) {
    __shared__ bf16_t Pl[16][1032];
    __shared__ float  rmax[8][16];
    __shared__ float  rsum[8][16];

    const int bx   = blockIdx.x;
    const int b    = bx & 7;
    const int n0   = ((bx >> 3) & 63) * 16;
    const int hc   = bx >> 9;           // head within pass
    const int h    = h0 + hc;           // global head
    const int tid  = threadIdx.x;
    const int w    = tid >> 6;          // 0..7 col-waves
    const int lane = tid & 63;
    const int l15  = lane & 15;
    const int quad = lane >> 4;

    const f32x4 fz = {0.f, 0.f, 0.f, 0.f};
    const long qoff = (long)(b * 1024 + n0 + l15) * 768 + h * 64 + quad * 8;
    const long koff = (long)(b * 1024) * 768 + h * 64 + quad * 8;

    // ---- S = Q K^T: this wave covers cols m = w*128 + f*16 + l15
    f32x4 s[8];
#pragma unroll
    for (int f = 0; f < 8; ++f) s[f] = fz;
    const bf16x8 qa0 = *(const bf16x8*)(Q + qoff);
    const bf16x8 qa1 = *(const bf16x8*)(Q + qoff + 32);
#pragma unroll
    for (int f = 0; f < 8; ++f) {
        const int m = w * 128 + f * 16 + l15;
        const bf16_t* kp = Kp + koff + (long)m * 768;
        s[f] = mfma16(qa0, *(const bf16x8*)kp, s[f]);
        s[f] = mfma16(qa1, *(const bf16x8*)(kp + 32), s[f]);
    }
    // ---- softmax over m; lane owns rows quad*4 + r
    float rm[4] = {-3e38f, -3e38f, -3e38f, -3e38f};
#pragma unroll
    for (int f = 0; f < 8; ++f)
#pragma unroll
        for (int r = 0; r < 4; ++r) {
            s[f][r] *= 0.125f;
            rm[r] = fmaxf(rm[r], s[f][r]);
        }
#pragma unroll
    for (int off = 1; off < 16; off <<= 1)
#pragma unroll
        for (int r = 0; r < 4; ++r) rm[r] = fmaxf(rm[r], __shfl_xor(rm[r], off));
    if (l15 == 0) {
#pragma unroll
        for (int r = 0; r < 4; ++r) rmax[w][quad * 4 + r] = rm[r];
    }
    __syncthreads();
    float gm[4];
#pragma unroll
    for (int r = 0; r < 4; ++r) {
        float mx = rmax[0][quad * 4 + r];
#pragma unroll
        for (int w2 = 1; w2 < 8; ++w2) mx = fmaxf(mx, rmax[w2][quad * 4 + r]);
        gm[r] = mx;
    }
    float ps[4] = {0.f, 0.f, 0.f, 0.f};
#pragma unroll
    for (int f = 0; f < 8; ++f)
#pragma unroll
        for (int r = 0; r < 4; ++r) {
            const float p = __expf(s[f][r] - gm[r]);
            s[f][r] = p;
            ps[r] += p;
        }
#pragma unroll
    for (int off = 1; off < 16; off <<= 1)
#pragma unroll
        for (int r = 0; r < 4; ++r) ps[r] += __shfl_xor(ps[r], off);
    if (l15 == 0) {
#pragma unroll
        for (int r = 0; r < 4; ++r) rsum[w][quad * 4 + r] = ps[r];
    }
    __syncthreads();
#pragma unroll
    for (int r = 0; r < 4; ++r) {
        float ss = 0.f;
#pragma unroll
        for (int w2 = 0; w2 < 8; ++w2) ss += rsum[w2][quad * 4 + r];
        gm[r] = 1.0f / ss;
    }
#pragma unroll
    for (int f = 0; f < 8; ++f)
#pragma unroll
        for (int r = 0; r < 4; ++r)
            Pl[quad * 4 + r][w * 128 + f * 16 + l15] = (bf16_t)(s[f][r] * gm[r]);
    __syncthreads();

    // ---- coalesced store of the 16x1024 P tile (32 threads per row)
    const long pbase = ((long)b * 1024 + n0) * ldP + (long)hc * 1024;
    const int rr = tid >> 5;
    const int c0 = (tid & 31) * 32;
    bf16_t* dst = P + pbase + (long)rr * ldP + c0;
#pragma unroll
    for (int u = 0; u < 4; ++u)
        *(bf16x8*)(dst + u * 8) = *(const bf16x8*)(&Pl[rr][c0 + u * 8]);
}

// ---------------------------------------------------------------- launch
extern "C" void kernel_launch(void* const* d_in, const int* in_sizes, int n_in,
                              void* d_out, int out_size, void* d_ws, size_t ws_size,
                              hipStream_t stream) {
    (void)in_sizes; (void)n_in; (void)out_size;

    const void* x    = d_in[0];
    const void* y    = d_in[1];
    const void* ln1g = d_in[2];
    const void* ln1b = d_in[3];
    const void* ln2g = d_in[4];
    const void* ln2b = d_in[5];
    const void* ln3g = d_in[6];
    const void* ln3b = d_in[7];
    const void* wq   = d_in[8];
    const void* bq   = d_in[9];
    const void* wk   = d_in[10];
    const void* bk   = d_in[11];
    const void* wv   = d_in[12];
    const void* bv   = d_in[13];
    const void* wi   = d_in[14];
    const void* bi   = d_in[15];
    const void* wo   = d_in[16];
    const void* bo   = d_in[17];

    // ---- workspace layout (r8 layout, verified at 842 us) ----
    // fixed block = 94,380,032 B; per-pass block = (8192+6144) rows of padded
    // pitch ldP = G*1024+64, i.e. need = 96,215,040 + G*29,360,128.
    char* ws = (char*)d_ws;
    bf16_t* xn    = (bf16_t*)(ws + 0);           // 12,582,912
    bf16_t* ynb   = (bf16_t*)(ws + 12582912);    // 12,582,912
    bf16_t* qb    = (bf16_t*)(ws + 25165824);    // 12,582,912 (Q; later h_pre)
    bf16_t* kb    = (bf16_t*)(ws + 37748736);    // 12,582,912 (K; later hn)
    bf16_t* W2T   = (bf16_t*)(ws + 50331648);    // 14,155,776
    bf16_t* wqT   = (bf16_t*)(ws + 64487424);    // 1,179,648
    bf16_t* wkT   = (bf16_t*)(ws + 65667072);
    bf16_t* wiT   = (bf16_t*)(ws + 66846720);
    bf16_t* woT   = (bf16_t*)(ws + 68026368);
    float*  bvs   = (float*) (ws + 69206016);    // 3,072
    int*    flag  = (int*)   (ws + 69210112);    // flag[0]=fp32 mode, flag[1]=0
    float*  dxf   = (float*) (ws + 69214208);    // 25,165,824 (multi-pass only)

    static const int GS[5] = {12, 6, 4, 3, 2};
    int G = 2;
    for (int i = 0; i < 5; ++i) {
        const unsigned long long need =
            96215040ULL + (unsigned long long)GS[i] * 29360128ULL;
        if (need <= (unsigned long long)ws_size) { G = GS[i]; break; }
    }
    const int KK  = G * 1024;
    const int ldP = KK + 64;
    bf16_t* Pcat = (bf16_t*)(ws + 94380032);                 // 8192 x ldP
    bf16_t* VTc  = Pcat + (size_t)8192 * ldP;                // 6144 x ldP
    bf16_t* hpre = qb;
    bf16_t* hn   = kb;
    bf16_t* mid  = Pcat;     // 12.6 MB, reused after attention
    const int* F = flag;
    const int* Z = flag + 1;

    detect_dtype<<<1, 256, 0, stream>>>(x, flag);

    transpose_w4<<<dim3(24, 24, 4), 256, 0, stream>>>(wq, wk, wi, wo,
                                                      wqT, wkT, wiT, woT, F);
    transpose_wv<<<dim3(24, 24, 12), dim3(32, 8), 0, stream>>>(wv, W2T, F);
    bvsum_k<<<3, 256, 0, stream>>>(bv, bvs, F);

    // LN(x) -> xn and LN(y) -> ynb (+ direct emit of output 1 to d_out+n)
    ln_xy<<<16384, 256, 0, stream>>>(x, y, xn, ynb, ln1g, ln1b, ln2g, ln2b,
                                     d_out, F);

    // Q = xn @ wq + bq; K = yn @ wk + bk  (1536 blocks of 64x128)
    gemm_qk<<<dim3(6, 128, 2), 256, 0, stream>>>(xn, ynb, wqT, wkT, qb, kb, bq, bk, F);

    // attention middle, cat-K route (r8 engine):
    //   Pcat[b][n][hc*1024+m] = softmax(Q K^T / 8)
    //   VTcat[b][e][hc*1024+m] = (yn @ wv_h)^T
    //   dx_b = Pcat_b @ VTcat_b^T  (K = G*1024 deep; epilogue -> h_pre)
    const int npass = 12 / G;
    for (int p = 0; p < npass; ++p) {
        const int h0 = p * G;
        fused_S<<<512 * G, 512, 0, stream>>>(qb, kb, Pcat, h0, ldP);
        gemm_vt<<<dim3(8, 96, G), 256, 0, stream>>>(W2T, ynb, VTc, h0, ldP);
        const int mode = (npass == 1) ? 3 : (p == 0 ? 0 : (p == npass - 1 ? 2 : 1));
        gemm_dx<<<dim3(8, 96), 256, 0, stream>>>(Pcat, VTc, dxf, xn, bvs, hpre,
                                                 KK, ldP, mode);
    }

    ln768<<<8192, 256, 0, stream>>>(hpre, hn, ln3g, ln3b, Z, F);

    gemm_bt<<<dim3(6, 128), 256, 0, stream>>>(hn, wiT, mid, 768, 768, 768, 768,
                                              bi, F, nullptr, 1, nullptr);
    // final GEMM writes output 0 (h + mlp) directly to d_out in detected dtype
    gemm_bt<<<dim3(6, 128), 256, 0, stream>>>(mid, woT, nullptr, 768, 768, 768, 768,
                                              bo, F, hn, 0, d_out);
}